// Round 5
// baseline (41.134 us; speedup 1.0000x reference)
//
#include <hip/hip_runtime.h>

// Problem constants (from reference setup_inputs)
#define BB 32
#define CC 64
#define HH 224
#define WW 224
#define HO 112
#define WO 112
#define OPH 17   // ceil((32 + 2 - 1) / 2)
#define OPW 17

#define IMG_F4   (CC * HO * WO / 4)   // 200704 float4 per image (= 1024 * 196)
#define CH_F4    (HO * WO / 4)        // 3136 float4 per channel
#define ROW_F4   (WO / 4)             // 28 float4 per output row
#define TOTAL_F4 (BB * IMG_F4)        // 6422528 float4 total
#define F4_PER_THREAD 4
#define TILE_F4  (256 * F4_PER_THREAD)      // 1024 float4 per block
#define BLK_PER_IMG (IMG_F4 / TILE_F4)      // 196 blocks per image (exact)

typedef float f32x4 __attribute__((ext_vector_type(4)));

// Single fused pass, 4 float4 per thread (256-strided for coalescing, 4 loads
// in flight per wave). Copy stale pooled output; recompute elements inside the
// per-image dirty 17x17 output window. Tail of d_out gets new_loc as float32.
__global__ __launch_bounds__(256)
void IncMaxPool_fused_kernel(const float* __restrict__ in,
                             const f32x4* __restrict__ prev,
                             const int* __restrict__ loc,
                             f32x4* __restrict__ out) {
    const int b    = blockIdx.x / BLK_PER_IMG;          // block-uniform image idx
    const int base = blockIdx.x * TILE_F4 + threadIdx.x;

    const int l0 = loc[b * 2 + 0];
    const int l1 = loc[b * 2 + 1];
    const int oy = min(max(l0 >> 1, 0), HO - OPH);
    const int ox = min(max(l1 >> 1, 0), WO - OPW);

    // issue all 4 loads before any use (4 vmem in flight per wave)
    f32x4 v[F4_PER_THREAD];
    #pragma unroll
    for (int k = 0; k < F4_PER_THREAD; ++k)
        v[k] = prev[base + k * 256];

    const float* imgbase = in + (size_t)b * CC * (HH * WW);

    #pragma unroll
    for (int k = 0; k < F4_PER_THREAD; ++k) {
        const int t  = base + k * 256;
        const int r0 = t - b * IMG_F4;          // f4 index within image
        const int c  = r0 / CH_F4;
        const int r1 = r0 - c * CH_F4;
        const int y  = r1 / ROW_F4;
        const int x4 = (r1 - y * ROW_F4) * 4;

        if (y >= oy && y < oy + OPH && (x4 + 3) >= ox && x4 <= (ox + OPW - 1)) {
            const float* ib = imgbase + (size_t)c * (HH * WW) + (size_t)(y * 2) * WW;
            #pragma unroll
            for (int j = 0; j < 4; ++j) {
                const int x = x4 + j;
                if (x >= ox && x < ox + OPW) {
                    const float2 a = *(const float2*)(ib + x * 2);        // row y*2
                    const float2 d = *(const float2*)(ib + WW + x * 2);   // row y*2+1
                    v[k][j] = fmaxf(fmaxf(a.x, a.y), fmaxf(d.x, d.y));
                }
            }
        }
    }

    #pragma unroll
    for (int k = 0; k < F4_PER_THREAD; ++k)
        out[base + k * 256] = v[k];

    // new_loc tail: 32 (oy, ox) pairs as floats
    if (base < BB) {
        const int m0 = loc[base * 2 + 0];
        const int m1 = loc[base * 2 + 1];
        float* locout = (float*)out + (size_t)BB * CC * HO * WO;
        locout[base * 2 + 0] = (float)min(max(m0 >> 1, 0), HO - OPH);
        locout[base * 2 + 1] = (float)min(max(m1 >> 1, 0), WO - OPW);
    }
}

extern "C" void kernel_launch(void* const* d_in, const int* in_sizes, int n_in,
                              void* d_out, int out_size, void* d_ws, size_t ws_size,
                              hipStream_t stream) {
    const float* in_tensor  = (const float*)d_in[0];
    const f32x4* out_tensor = (const f32x4*)d_in[1];
    const int*   loc        = (const int*)d_in[2];
    f32x4* out = (f32x4*)d_out;

    IncMaxPool_fused_kernel<<<TOTAL_F4 / TILE_F4, 256, 0, stream>>>(in_tensor, out_tensor, loc, out);
}

// Round 6
// 37.765 us; speedup vs baseline: 1.0892x; 1.0892x over previous
//
#include <hip/hip_runtime.h>

// Problem constants (from reference setup_inputs)
#define BB 32
#define CC 64
#define HH 224
#define WW 224
#define HO 112
#define WO 112
#define OPH 17   // ceil((32 + 2 - 1) / 2)
#define OPW 17

#define IMG_F4   (CC * HO * WO / 4)   // 200704 float4 per image (= 256 * 784)
#define CH_F4    (HO * WO / 4)        // 3136 float4 per channel
#define ROW_F4   (WO / 4)             // 28 float4 per output row
#define BLK_PER_IMG (IMG_F4 / 256)    // 784 blocks per image (exact)

// Single fused pass (R2 structure — best measured 38.25us), with block-uniform
// image index from blockIdx.y so loc load + patch-origin math lives in SGPRs.
// Copy stale pooled output; recompute elements inside the per-image dirty
// 17x17 output window. Tail of d_out gets new_loc as float32.
__global__ __launch_bounds__(256)
void IncMaxPool_fused_kernel(const float* __restrict__ in,
                             const float4* __restrict__ prev,
                             const int* __restrict__ loc,
                             float4* __restrict__ out) {
    const int b  = blockIdx.y;                          // block-uniform image idx
    const int r0 = blockIdx.x * 256 + threadIdx.x;      // float4 idx within image
    const int tid = b * IMG_F4 + r0;                    // global float4 idx

    // scalar (SGPR) patch origin
    const int l0 = loc[b * 2 + 0];
    const int l1 = loc[b * 2 + 1];
    const int oy = min(max(l0 >> 1, 0), HO - OPH);
    const int ox = min(max(l1 >> 1, 0), WO - OPW);

    // decompose within-image index -> (c, y, x4)
    const int c  = r0 / CH_F4;
    const int r1 = r0 - c * CH_F4;
    const int y  = r1 / ROW_F4;
    const int x4 = (r1 - y * ROW_F4) * 4;

    float4 v = prev[tid];

    if (y >= oy && y < oy + OPH && (x4 + 3) >= ox && x4 <= (ox + OPW - 1)) {
        const float* ib = in + (size_t)(b * CC + c) * (HH * WW) + (size_t)(y * 2) * WW;
        float r[4] = {v.x, v.y, v.z, v.w};
        #pragma unroll
        for (int j = 0; j < 4; ++j) {
            const int x = x4 + j;
            if (x >= ox && x < ox + OPW) {
                const float2 a = *(const float2*)(ib + x * 2);        // row y*2
                const float2 d = *(const float2*)(ib + WW + x * 2);   // row y*2+1
                r[j] = fmaxf(fmaxf(a.x, a.y), fmaxf(d.x, d.y));
            }
        }
        v = make_float4(r[0], r[1], r[2], r[3]);
    }

    out[tid] = v;

    // new_loc tail: 32 (oy, ox) pairs as floats (one block handles all)
    if (blockIdx.y == 0 && blockIdx.x == 0 && threadIdx.x < BB) {
        const int t  = threadIdx.x;
        const int m0 = loc[t * 2 + 0];
        const int m1 = loc[t * 2 + 1];
        float* locout = (float*)out + (size_t)BB * CC * HO * WO;
        locout[t * 2 + 0] = (float)min(max(m0 >> 1, 0), HO - OPH);
        locout[t * 2 + 1] = (float)min(max(m1 >> 1, 0), WO - OPW);
    }
}

extern "C" void kernel_launch(void* const* d_in, const int* in_sizes, int n_in,
                              void* d_out, int out_size, void* d_ws, size_t ws_size,
                              hipStream_t stream) {
    const float*  in_tensor  = (const float*)d_in[0];
    const float4* out_tensor = (const float4*)d_in[1];
    const int*    loc        = (const int*)d_in[2];
    float4* out = (float4*)d_out;

    dim3 grid(BLK_PER_IMG, BB);
    IncMaxPool_fused_kernel<<<grid, 256, 0, stream>>>(in_tensor, out_tensor, loc, out);
}